// Round 9
// baseline (3028.876 us; speedup 1.0000x reference)
//
#include <hip/hip_runtime.h>
#include <stdint.h>

#define B_  64
#define T_  512
#define I_  512
#define H_  1024
#define KW  1536   // rows of W_t = I_ + H_

#define LDS_BYTES 98816

typedef __attribute__((ext_vector_type(8))) short bf16x8;
typedef __attribute__((ext_vector_type(4))) float f32x4;

// ---- ws layout (bytes) ----
#define OFF_WT   ((size_t)0)                        // 4096*1536*2 = 12,582,912
#define OFF_XB   ((size_t)(16u << 20))              // x bf16: 33,554,432
#define OFF_HB   (OFF_XB + (size_t)33554432)        // tagged h: 2 par * 4 grp * 16 * 1024 * 2B
#define WS_NEED  (OFF_HB + (size_t)262144)

__device__ __forceinline__ unsigned short f2bf(float x) {
  unsigned u = __float_as_uint(x);
  u += 0x7FFFu + ((u >> 16) & 1u);        // RNE
  return (unsigned short)(u >> 16);
}
__device__ __forceinline__ float sigm(float x) {
  return 1.0f / (1.0f + __expf(-x));
}
__device__ __forceinline__ float fast_tanh(float x) {
  const float e2 = __expf(2.0f * x);
  return 1.0f - 2.0f / (e2 + 1.0f);
}
__device__ __forceinline__ bf16x8 bc8(int4 v) {
  union { int4 i; bf16x8 b; } u; u.i = v; return u.b;
}

// ============ kernel 0: pack [U;V] -> W_t[col][k] bf16 (transposed) ============
__global__ __launch_bounds__(256) void pack_w_kernel(
    const float* __restrict__ U0, const float* __restrict__ U1,
    const float* __restrict__ U2, const float* __restrict__ U3,
    const float* __restrict__ V0, const float* __restrict__ V1,
    const float* __restrict__ V2, const float* __restrict__ V3,
    short* __restrict__ Wt)
{
  __shared__ short sl[64][65];
  const int c0 = blockIdx.x * 64;
  const int k0 = blockIdx.y * 64;
  const int g  = c0 >> 10;
  const int h0 = c0 & 1023;
  const float* srcU = (g == 0 ? U0 : g == 1 ? U1 : g == 2 ? U2 : U3);
  const float* srcV = (g == 0 ? V0 : g == 1 ? V1 : g == 2 ? V2 : V3);
  const float* src  = (k0 < 512) ? (srcU + (size_t)k0 * H_)
                                 : (srcV + (size_t)(k0 - 512) * H_);
  const int tid = threadIdx.x;
  const int cl = tid & 63;
  const int r4 = tid >> 6;
  #pragma unroll
  for (int r = 0; r < 16; ++r) {
    const int kl = r * 4 + r4;
    sl[kl][cl] = (short)f2bf(src[(size_t)kl * H_ + h0 + cl]);
  }
  __syncthreads();
  #pragma unroll
  for (int r = 0; r < 16; ++r) {
    const int cl2 = r * 4 + r4;
    Wt[(size_t)(c0 + cl2) * KW + k0 + cl] = sl[cl][cl2];
  }
}

// ============ kernel 1: x fp32 -> bf16 ============
__global__ __launch_bounds__(256) void xcvt(
    const float* __restrict__ x, short* __restrict__ xb)
{
  const int nt = 524288;
  const int idx = blockIdx.x * 256 + threadIdx.x;
  #pragma unroll
  for (int i = 0; i < 8; ++i) {
    const int j = idx + i * nt;
    const float4 v = ((const float4*)x)[j];
    uint2 pk;
    pk.x = (unsigned)f2bf(v.x) | ((unsigned)f2bf(v.y) << 16);
    pk.y = (unsigned)f2bf(v.z) | ((unsigned)f2bf(v.w) << 16);
    ((uint2*)xb)[j] = pk;
  }
}

// fragment address (shorts): slot XOR-swizzled within unit
#define FR_ADDR(unit, slot) ((((unit) * 64) + ((slot) ^ ((unit) & 7))) * 8)
#define FOFF(f) ((((f) >> 7) * 1024) + (((f) & 127) * 8))
#define SADR(f) FR_ADDR((((f) & 127) >> 2), ((((f) >> 7) << 2) | ((f) & 3)))

#define XRD_(vv, ew) ((((unsigned)(vv).x ^ (ew)) | ((unsigned)(vv).y ^ (ew)) | \
                       ((unsigned)(vv).z ^ (ew)) | ((unsigned)(vv).w ^ (ew))) & 0x00010001u)
#define LDH(vv, p) asm volatile("global_load_dwordx4 %0, %1, off sc0 sc1" : "=&v"(vv) : "v"(p));
#define LDX(vv, p) asm volatile("global_load_dwordx4 %0, %1, off" : "=&v"(vv) : "v"(p));

#define RETRY_(hsrc, ew) \
  for (;;) { \
    LDH(sp0, (hsrc) + foff0) LDH(sp1, (hsrc) + foff1) \
    LDH(sp2, (hsrc) + foff2) LDH(sp3, (hsrc) + foff3) \
    asm volatile("s_waitcnt vmcnt(0)" ::: "memory"); \
    __builtin_amdgcn_sched_barrier(0); \
    if (__all((XRD_(sp0, ew) | XRD_(sp1, ew) | XRD_(sp2, ew) | XRD_(sp3, ew)) == 0u)) break; \
    asm volatile("s_sleep 1" ::: "memory"); \
  }

// One half-round for one group. All in-loop VMEM is inline asm -> exact vmcnt FIFO:
// per half-round ops: [xload x2, spec x4, hstore x1, outstore x1]
#define HALF(SH, GL, HBG, XROW, B0, XACCA, XACCB, CST, HLAST, XVA, XVB, SPECHBG, SPECT, TCUR, DOCHK) \
{ \
  const unsigned ew = (((TCUR) >> 1) & 1) ? 0x00010001u : 0u; \
  const short* hsrc = (HBG) + (((TCUR) & 1) ? 65536 : 0); \
  bool ok = (DOCHK); \
  if (ok) { \
    asm volatile("s_waitcnt vmcnt(2)" ::: "memory"); \
    __builtin_amdgcn_sched_barrier(0); \
    ok = __all((XRD_(sp0, ew) | XRD_(sp1, ew) | XRD_(sp2, ew) | XRD_(sp3, ew)) == 0u); \
  } \
  if (!ok) { RETRY_(hsrc, ew) } \
  *(int4*)((SH) + saddr0) = sp0; \
  *(int4*)((SH) + saddr1) = sp1; \
  *(int4*)((SH) + saddr2) = sp2; \
  *(int4*)((SH) + saddr3) = sp3; \
  { const int tn = ((TCUR) + 1 < T_) ? (TCUR) + 1 : T_ - 1; \
    const short* xp = (XROW) + (size_t)tn * I_; \
    LDX(XVA, xp) LDX(XVB, xp + 32) } \
  { const short* ss = (SPECHBG) + (((SPECT) & 1) ? 65536 : 0); \
    LDH(sp0, ss + foff0) LDH(sp1, ss + foff1) LDH(sp2, ss + foff2) LDH(sp3, ss + foff3) } \
  __syncthreads(); \
  f32x4 accA = XACCA, accB = XACCB; \
  { \
    bf16x8 af; \
    af = *(const bf16x8*)((SH) + FR_ADDR(kqe * 4 + 0, slot_r)); \
    accA = __builtin_amdgcn_mfma_f32_16x16x32_bf16(af, vfr0[0], accA, 0, 0, 0); \
    accB = __builtin_amdgcn_mfma_f32_16x16x32_bf16(af, vfr1[0], accB, 0, 0, 0); \
    af = *(const bf16x8*)((SH) + FR_ADDR(kqe * 4 + 1, slot_r)); \
    accA = __builtin_amdgcn_mfma_f32_16x16x32_bf16(af, vfr0[1], accA, 0, 0, 0); \
    accB = __builtin_amdgcn_mfma_f32_16x16x32_bf16(af, vfr1[1], accB, 0, 0, 0); \
    af = *(const bf16x8*)((SH) + FR_ADDR(kqe * 4 + 2, slot_r)); \
    accA = __builtin_amdgcn_mfma_f32_16x16x32_bf16(af, vfr0[2], accA, 0, 0, 0); \
    accB = __builtin_amdgcn_mfma_f32_16x16x32_bf16(af, vfr1[2], accB, 0, 0, 0); \
    af = *(const bf16x8*)((SH) + FR_ADDR(kqe * 4 + 3, slot_r)); \
    accA = __builtin_amdgcn_mfma_f32_16x16x32_bf16(af, vfr0[3], accA, 0, 0, 0); \
    accB = __builtin_amdgcn_mfma_f32_16x16x32_bf16(af, vfr1[3], accB, 0, 0, 0); \
  } \
  { \
    (GL)[(l16 * 4 + 0) * 260 + cit * 8 + kqe] = accA[0]; \
    (GL)[(l16 * 4 + 1) * 260 + cit * 8 + kqe] = accA[1]; \
    (GL)[(l16 * 4 + 2) * 260 + cit * 8 + kqe] = accA[2]; \
    (GL)[(l16 * 4 + 3) * 260 + cit * 8 + kqe] = accA[3]; \
    (GL)[(l16 * 4 + 0) * 260 + (16 + cit) * 8 + kqe] = accB[0]; \
    (GL)[(l16 * 4 + 1) * 260 + (16 + cit) * 8 + kqe] = accB[1]; \
    (GL)[(l16 * 4 + 2) * 260 + (16 + cit) * 8 + kqe] = accB[2]; \
    (GL)[(l16 * 4 + 3) * 260 + (16 + cit) * 8 + kqe] = accB[3]; \
  } \
  __syncthreads(); \
  asm volatile("s_waitcnt vmcnt(4)" ::: "memory"); \
  __builtin_amdgcn_sched_barrier(0); \
  { \
    const bf16x8 xf0 = bc8(XVA), xf1 = bc8(XVB); \
    XACCA = (f32x4){bv0, bv0, bv0, bv0}; \
    XACCB = (f32x4){bv1, bv1, bv1, bv1}; \
    XACCA = __builtin_amdgcn_mfma_f32_16x16x32_bf16(xf0, ufr0[0], XACCA, 0, 0, 0); \
    XACCA = __builtin_amdgcn_mfma_f32_16x16x32_bf16(xf1, ufr0[1], XACCA, 0, 0, 0); \
    XACCB = __builtin_amdgcn_mfma_f32_16x16x32_bf16(xf0, ufr1[0], XACCB, 0, 0, 0); \
    XACCB = __builtin_amdgcn_mfma_f32_16x16x32_bf16(xf1, ufr1[1], XACCB, 0, 0, 0); \
  } \
  if (l < 16) { \
    const float* gr = (GL) + crow * 260; \
    const f32x4 a0 = *(const f32x4*)(gr + ccol * 8); \
    const f32x4 b0a = *(const f32x4*)(gr + ccol * 8 + 4); \
    const f32x4 a1 = *(const f32x4*)(gr + 64 + ccol * 8); \
    const f32x4 b1a = *(const f32x4*)(gr + 64 + ccol * 8 + 4); \
    const f32x4 a2 = *(const f32x4*)(gr + 128 + ccol * 8); \
    const f32x4 b2a = *(const f32x4*)(gr + 128 + ccol * 8 + 4); \
    const f32x4 a3 = *(const f32x4*)(gr + 192 + ccol * 8); \
    const f32x4 b3a = *(const f32x4*)(gr + 192 + ccol * 8 + 4); \
    const float s0 = a0[0]+a0[1]+a0[2]+a0[3]+b0a[0]+b0a[1]+b0a[2]+b0a[3]; \
    const float s1 = a1[0]+a1[1]+a1[2]+a1[3]+b1a[0]+b1a[1]+b1a[2]+b1a[3]; \
    const float s2 = a2[0]+a2[1]+a2[2]+a2[3]+b2a[0]+b2a[1]+b2a[2]+b2a[3]; \
    const float s3 = a3[0]+a3[1]+a3[2]+a3[3]+b3a[0]+b3a[1]+b3a[2]+b3a[3]; \
    const float i_ = sigm(s0), f_ = sigm(s1), g_ = sigm(s2), o_ = sigm(s3); \
    CST = f_ * CST + i_ * g_; \
    const float hv = o_ * fast_tanh(CST); \
    HLAST = hv; \
    unsigned hu = (unsigned)f2bf(hv); \
    hu = (hu & ~1u) | (unsigned)((((TCUR) + 1) >> 1) & 1); \
    short* hd = (HBG) + ((((TCUR) + 1) & 1) ? 65536 : 0) + crow * 1024 + base8 + ccol; \
    asm volatile("global_store_short %0, %1, off sc0 sc1" :: "v"(hd), "v"(hu) : "memory"); \
    float* op = out + (((size_t)((B0) + crow)) << 19) + (size_t)(TCUR) * H_ + base8 + ccol; \
    asm volatile("global_store_dword %0, %1, off" :: "v"(op), "v"(hv) : "memory"); \
  } \
}

// ============ kernel 2: dual-group persistent recurrence ============
__global__ __launch_bounds__(512, 1) void lstm_rec(
    const short* __restrict__ Wt, const short* __restrict__ xb,
    const float* __restrict__ b0g, const float* __restrict__ b1g,
    const float* __restrict__ b2g, const float* __restrict__ b3g,
    short* __restrict__ hb, float* __restrict__ out)
{
  extern __shared__ char smem[];
  short* shP = (short*)smem;                       // 32 KiB h frags, group P
  short* shQ = (short*)(smem + 32768);             // 32 KiB h frags, group Q
  float* glP = (float*)(smem + 65536);             // [16][260] f32 partials, P
  float* glQ = (float*)(smem + 82176);             // [16][260] f32 partials, Q

  const int tid = threadIdx.x;
  const int blk = blockIdx.x;
  const int pair = blk >> 7;                       // 0: groups {0,1}; 1: {2,3}
  const int bi = blk & 127;
  const int base8 = bi * 8;                        // 8 h-cols per block per gate
  const int w = tid >> 6, l = tid & 63;
  const int kqe = w;                               // K-eighth (128 of V-K, 64 of x-K)
  const int cit = l & 15, l16 = l >> 4;
  const int slot_r = (cit << 2) | l16;
  const int Pg = pair * 2, Qg = pair * 2 + 1;
  const int b0P = Pg * 16, b0Q = Qg * 16;

  short* hbP = hb + Pg * 16384;                    // group base (shorts); +65536 = parity 1
  short* hbQ = hb + Qg * 16384;

  // ---- one-time: V/U fragments -> registers (shared by both groups) ----
  bf16x8 vfr0[4], vfr1[4], ufr0[2], ufr1[2];
  float bv0, bv1;
  {
    const int g0 = cit >> 3, c8 = cit & 7;
    const short* wpa = Wt + (size_t)(g0 * 1024 + base8 + c8) * KW;        // gates 0/1
    const short* wpb = Wt + (size_t)((2 + g0) * 1024 + base8 + c8) * KW;  // gates 2/3
    #pragma unroll
    for (int j = 0; j < 4; ++j) {
      vfr0[j] = *(const bf16x8*)(wpa + 512 + kqe * 128 + j * 32 + l16 * 8);
      vfr1[j] = *(const bf16x8*)(wpb + 512 + kqe * 128 + j * 32 + l16 * 8);
    }
    #pragma unroll
    for (int j = 0; j < 2; ++j) {
      ufr0[j] = *(const bf16x8*)(wpa + kqe * 64 + j * 32 + l16 * 8);
      ufr1[j] = *(const bf16x8*)(wpb + kqe * 64 + j * 32 + l16 * 8);
    }
    const float* bpa = g0 ? b1g : b0g;
    const float* bpb = g0 ? b3g : b2g;
    bv0 = (kqe == 0) ? bpa[base8 + c8] : 0.0f;
    bv1 = (kqe == 0) ? bpb[base8 + c8] : 0.0f;
  }

  // h-frag loader geometry (4 frags/thread cover the group's 32KB h)
  const int f0_ = tid, f1_ = 512 + tid, f2_ = 1024 + tid, f3_ = 1536 + tid;
  const int foff0 = FOFF(f0_), foff1 = FOFF(f1_), foff2 = FOFF(f2_), foff3 = FOFF(f3_);
  const int saddr0 = SADR(f0_), saddr1 = SADR(f1_), saddr2 = SADR(f2_), saddr3 = SADR(f3_);

  // x fragment row pointers (direct per-lane loads, no LDS)
  const short* xrowP = xb + (size_t)(b0P + cit) * T_ * I_ + kqe * 64 + l16 * 8;
  const short* xrowQ = xb + (size_t)(b0Q + cit) * T_ * I_ + kqe * 64 + l16 * 8;

  // combine lane geometry (lanes 0..15 of EVERY wave -> uniform vmcnt)
  const int crow = 2 * w + (l >> 3);
  const int ccol = l & 7;

  float cP = 0.0f, cQ = 0.0f, hlP = 0.0f, hlQ = 0.0f;
  int4 sp0, sp1, sp2, sp3;
  int4 xvP0, xvP1, xvQ0, xvQ1;
  f32x4 xaccP0, xaccP1, xaccQ0, xaccQ1;

  // ---- prologue: xu(0) for both groups from direct x frags ----
  LDX(xvP0, xrowP) LDX(xvP1, xrowP + 32)
  LDX(xvQ0, xrowQ) LDX(xvQ1, xrowQ + 32)
  asm volatile("s_waitcnt vmcnt(0)" ::: "memory");
  __builtin_amdgcn_sched_barrier(0);
  {
    const bf16x8 p0 = bc8(xvP0), p1 = bc8(xvP1), q0 = bc8(xvQ0), q1 = bc8(xvQ1);
    xaccP0 = (f32x4){bv0, bv0, bv0, bv0};
    xaccP1 = (f32x4){bv1, bv1, bv1, bv1};
    xaccQ0 = (f32x4){bv0, bv0, bv0, bv0};
    xaccQ1 = (f32x4){bv1, bv1, bv1, bv1};
    xaccP0 = __builtin_amdgcn_mfma_f32_16x16x32_bf16(p0, ufr0[0], xaccP0, 0, 0, 0);
    xaccP0 = __builtin_amdgcn_mfma_f32_16x16x32_bf16(p1, ufr0[1], xaccP0, 0, 0, 0);
    xaccP1 = __builtin_amdgcn_mfma_f32_16x16x32_bf16(p0, ufr1[0], xaccP1, 0, 0, 0);
    xaccP1 = __builtin_amdgcn_mfma_f32_16x16x32_bf16(p1, ufr1[1], xaccP1, 0, 0, 0);
    xaccQ0 = __builtin_amdgcn_mfma_f32_16x16x32_bf16(q0, ufr0[0], xaccQ0, 0, 0, 0);
    xaccQ0 = __builtin_amdgcn_mfma_f32_16x16x32_bf16(q1, ufr0[1], xaccQ0, 0, 0, 0);
    xaccQ1 = __builtin_amdgcn_mfma_f32_16x16x32_bf16(q0, ufr1[0], xaccQ1, 0, 0, 0);
    xaccQ1 = __builtin_amdgcn_mfma_f32_16x16x32_bf16(q1, ufr1[1], xaccQ1, 0, 0, 0);
  }

  for (int t = 0; t < T_; ++t) {
    HALF(shP, glP, hbP, xrowP, b0P, xaccP0, xaccP1, cP, hlP, xvP0, xvP1, hbQ, t,     t, (t > 0))
    HALF(shQ, glQ, hbQ, xrowQ, b0Q, xaccQ0, xaccQ1, cQ, hlQ, xvQ0, xvQ1, hbP, t + 1, t, true)
  }

  // ---- finals: h_T, c_T ----
  if (l < 16) {
    const size_t fb = (size_t)B_ * T_ * H_;
    float* p1 = out + fb + (size_t)(b0P + crow) * H_ + base8 + ccol;
    float* p2 = out + fb + (size_t)B_ * H_ + (size_t)(b0P + crow) * H_ + base8 + ccol;
    float* q1 = out + fb + (size_t)(b0Q + crow) * H_ + base8 + ccol;
    float* q2 = out + fb + (size_t)B_ * H_ + (size_t)(b0Q + crow) * H_ + base8 + ccol;
    asm volatile("global_store_dword %0, %1, off" :: "v"(p1), "v"(hlP) : "memory");
    asm volatile("global_store_dword %0, %1, off" :: "v"(p2), "v"(cP) : "memory");
    asm volatile("global_store_dword %0, %1, off" :: "v"(q1), "v"(hlQ) : "memory");
    asm volatile("global_store_dword %0, %1, off" :: "v"(q2), "v"(cQ) : "memory");
  }
}

extern "C" void kernel_launch(void* const* d_in, const int* in_sizes, int n_in,
                              void* d_out, int out_size, void* d_ws, size_t ws_size,
                              hipStream_t stream)
{
  const float* x  = (const float*)d_in[0];
  const float* U0 = (const float*)d_in[1];
  const float* Vg0 = (const float*)d_in[2];
  const float* bg0 = (const float*)d_in[3];
  const float* U1 = (const float*)d_in[4];
  const float* Vg1 = (const float*)d_in[5];
  const float* bg1 = (const float*)d_in[6];
  const float* U2 = (const float*)d_in[7];
  const float* Vg2 = (const float*)d_in[8];
  const float* bg2 = (const float*)d_in[9];
  const float* U3 = (const float*)d_in[10];
  const float* Vg3 = (const float*)d_in[11];
  const float* bg3 = (const float*)d_in[12];

  if (ws_size < WS_NEED) return;  // diagnostic: leaves d_out poisoned

  char* ws = (char*)d_ws;
  short* Wt = (short*)(ws + OFF_WT);
  short* xb = (short*)(ws + OFF_XB);
  short* hb = (short*)(ws + OFF_HB);

  (void)hipFuncSetAttribute((const void*)lstm_rec,
                      hipFuncAttributeMaxDynamicSharedMemorySize, LDS_BYTES);

  // parity 0: zeros -> valid h(0)=0, tag 0. parity 1: 0x0101 -> stale until h(1) lands.
  (void)hipMemsetAsync(ws + OFF_HB, 0x00, 131072, stream);
  (void)hipMemsetAsync(ws + OFF_HB + 131072, 0x01, 131072, stream);
  pack_w_kernel<<<dim3(64, 24), 256, 0, stream>>>(U0, U1, U2, U3, Vg0, Vg1, Vg2, Vg3, Wt);
  xcvt<<<dim3(2048), 256, 0, stream>>>(x, xb);
  lstm_rec<<<dim3(256), 512, LDS_BYTES, stream>>>(
      Wt, xb, bg0, bg1, bg2, bg3, hb, (float*)d_out);
}